// Round 2
// baseline (6246.577 us; speedup 1.0000x reference)
//
#include <hip/hip_runtime.h>

// ---------------------------------------------------------------------------
// LSTM scan, B=64 L=512 D=1024, fully fused:
//   prep: transpose Wk,Wr -> f16 WkT,WrT [3072][1024]; x -> f16 xh; h0 -> h16[0..1]
//   scan: ONE persistent cooperative kernel, 512 steps, grid barrier per step.
//         Per block (256 thr): 16-batch x 16-d output tile. Wk AND Wr fragments
//         stationary in VGPRs. x@Wk MFMAs for step t+1 run in the barrier shadow.
// ws usage: ~80 MiB (no xproj buffer).
// ---------------------------------------------------------------------------

typedef float    f32x4 __attribute__((ext_vector_type(4)));
typedef _Float16 half8 __attribute__((ext_vector_type(8)));
typedef _Float16 half4 __attribute__((ext_vector_type(4)));

#define B_  64
#define L_  512
#define D_  1024
#define N3_ 3072

// ws layout (bytes)
#define WKT_OFF 0LL          // f16 [3072][1024]   6291456
#define WRT_OFF 6291456LL    // f16 [3072][1024]   6291456
#define XH_OFF  12582912LL   // f16 [B*L][1024]   67108864
#define H16_OFF 79691776LL   // f16 [2][64][1024]   262144
#define BAR_OFF 79953920LL   // unsigned[1024]        4096
// total 79958016 B ~= 76.3 MiB

__device__ __forceinline__ float sigmoidf_fast(float x) {
  return __builtin_amdgcn_rcpf(1.f + __builtin_amdgcn_exp2f(-1.4426950408889634f * x));
}
__device__ __forceinline__ float tanhf_fast(float x) {
  return 1.f - 2.f * __builtin_amdgcn_rcpf(1.f + __builtin_amdgcn_exp2f(2.8853900817779268f * x));
}

// ---------------- prep: transpose + f32->f16 (Wk and Wr) -------------------
__global__ __launch_bounds__(256) void transpose_f16(
    const float* __restrict__ Wk, const float* __restrict__ Wr,
    _Float16* __restrict__ WkT, _Float16* __restrict__ WrT)
{
  __shared__ float tile[32][33];
  int b = blockIdx.x;
  const float* in = Wk; _Float16* outp = WkT;
  if (b >= 3072) { b -= 3072; in = Wr; outp = WrT; }
  const int n0 = (b % 96) * 32;   // along 3072
  const int k0 = (b / 96) * 32;   // along 1024
  const int tx = threadIdx.x & 31, ty = threadIdx.x >> 5;
#pragma unroll
  for (int i = 0; i < 32; i += 8)
    tile[ty + i][tx] = in[(size_t)(k0 + ty + i) * N3_ + n0 + tx];
  __syncthreads();
#pragma unroll
  for (int i = 0; i < 32; i += 8)
    outp[(size_t)(n0 + ty + i) * D_ + k0 + tx] = (_Float16)tile[tx][ty + i];
}

// ---------------- prep: x -> f16, h0 -> BOTH h16 buffers -------------------
__global__ void convert_inputs(const f32x4* __restrict__ x, const f32x4* __restrict__ h0,
                               half4* __restrict__ xh, half4* __restrict__ h16a,
                               half4* __restrict__ h16b)
{
  const int NX = (B_ * L_ * D_) / 4;   // 8388608
  const int NH = (B_ * D_) / 4;        // 16384
  for (int i = blockIdx.x * blockDim.x + threadIdx.x; i < NX + NH;
       i += gridDim.x * blockDim.x) {
    if (i < NX) {
      xh[i] = __builtin_convertvector(x[i], half4);
    } else {
      half4 v = __builtin_convertvector(h0[i - NX], half4);
      h16a[i - NX] = v;
      h16b[i - NX] = v;
    }
  }
}

// ---------------- grid barrier (split arrive / wait) -----------------------
// 8 leaf counters (1/XCD-slot), root, 8 replicated monotone flags.
__device__ __forceinline__ void bar_arrive(unsigned* bar, int bid, unsigned target) {
  __syncthreads();   // every wave: s_waitcnt vmcnt(0) -> all h/out stores in L2
  if (threadIdx.x == 0) {
    const int g = bid & 7;
    // ACQ_REL release side: waitcnt + L2 writeback so our tile's stores are
    // agent-visible before the arrival is observable.
    unsigned a = __hip_atomic_fetch_add(&bar[g * 32], 1u, __ATOMIC_ACQ_REL,
                                        __HIP_MEMORY_SCOPE_AGENT);
    if (a == 31u) {
      unsigned r = __hip_atomic_fetch_add(&bar[256], 1u, __ATOMIC_ACQ_REL,
                                          __HIP_MEMORY_SCOPE_AGENT);
      if (r == 7u) {
        __hip_atomic_store(&bar[256], 0u, __ATOMIC_RELAXED, __HIP_MEMORY_SCOPE_AGENT);
#pragma unroll
        for (int i = 0; i < 8; ++i)
          __hip_atomic_store(&bar[i * 32], 0u, __ATOMIC_RELAXED, __HIP_MEMORY_SCOPE_AGENT);
#pragma unroll
        for (int i = 0; i < 8; ++i)
          __hip_atomic_store(&bar[288 + i * 32], target, __ATOMIC_RELEASE,
                             __HIP_MEMORY_SCOPE_AGENT);
      }
    }
  }
}
__device__ __forceinline__ void bar_wait(unsigned* bar, int bid, unsigned target) {
  if (threadIdx.x == 0) {
    while (__hip_atomic_load(&bar[288 + (bid & 7) * 32], __ATOMIC_RELAXED,
                             __HIP_MEMORY_SCOPE_AGENT) < target) {
      __builtin_amdgcn_s_sleep(1);
    }
    __builtin_amdgcn_fence(__ATOMIC_ACQUIRE, "agent");  // inv L1+L2 once
  }
  __syncthreads();
}

// ---------------- persistent scan ------------------------------------------
// 256 WGs = 4 b-tiles x 64 d-slices; 4 waves each own a K-slice of 256.
__global__ __launch_bounds__(256, 1) void lstm_scan(
    const _Float16* __restrict__ WkT,   // [3072][1024]
    const _Float16* __restrict__ WrT,   // [3072][1024]
    const _Float16* __restrict__ xh,    // [B*L][1024]
    const float*    __restrict__ c0,    // [64][1024]
    float*          __restrict__ out,   // [64][512][1024]
    _Float16*       __restrict__ h16,   // [2][64][1024]
    unsigned*       __restrict__ bar)
{
  const int tid = threadIdx.x, wave = tid >> 6, lane = tid & 63;
  const int bid = blockIdx.x;
  const int b0 = (bid & 3) * 16;
  const int d0 = (bid >> 2) * 16;
  const int l15 = lane & 15, l4h = lane >> 4;
  const int kbase = wave * 256;

  // stationary weight fragments: [gate][kt], B-frag layout (k=l4h*8+j, n=l15)
  half8 Wkf[3][8], Wrf[3][8];
#pragma unroll
  for (int g = 0; g < 3; ++g) {
    const _Float16* kr = WkT + (size_t)(g * D_ + d0 + l15) * D_ + kbase + l4h * 8;
    const _Float16* rr = WrT + (size_t)(g * D_ + d0 + l15) * D_ + kbase + l4h * 8;
#pragma unroll
    for (int kt = 0; kt < 8; ++kt) {
      Wkf[g][kt] = *(const half8*)(kr + kt * 32);
      Wrf[g][kt] = *(const half8*)(rr + kt * 32);
    }
  }

  const int rb = tid >> 4;   // batch within tile
  const int rd = tid & 15;   // d within tile
  float c = c0[(size_t)(b0 + rb) * D_ + d0 + rd];

  __shared__ float part[4][48][20];

  // A-frag source rows (m = b0+l15, k = kbase + kt*32 + l4h*8 + j)
  const _Float16* xrow = xh + ((size_t)(b0 + l15) * L_) * D_ + kbase + l4h * 8;
  const size_t hoff   = (size_t)(b0 + l15) * D_ + kbase + l4h * 8;
  const size_t outidx = ((size_t)(b0 + rb) * L_) * D_ + d0 + rd;
  const size_t hidx   = (size_t)(b0 + rb) * D_ + d0 + rd;

  _Float16* hc = h16;            // h_t   (both buffers pre-initialized with h0)
  _Float16* hn = h16 + B_ * D_;  // h_{t+1}

  f32x4 acc[3], acc2[3];
  // prologue: x-part for t=0
#pragma unroll
  for (int g = 0; g < 3; ++g) { f32x4 z = {0.f, 0.f, 0.f, 0.f}; acc[g] = z; acc2[g] = z; }
#pragma unroll
  for (int kt = 0; kt < 8; ++kt) {
    half8 afx = *(const half8*)(xrow + kt * 32);
#pragma unroll
    for (int g = 0; g < 3; ++g)
      acc[g] = __builtin_amdgcn_mfma_f32_16x16x32_f16(afx, Wkf[g][kt], acc[g], 0, 0, 0);
  }

  for (int t = 0; t < L_; ++t) {
    // h-part: finish gates for step t
    const _Float16* hrow = hc + hoff;
#pragma unroll
    for (int kt = 0; kt < 8; ++kt) {
      half8 afh = *(const half8*)(hrow + kt * 32);
#pragma unroll
      for (int g = 0; g < 3; ++g)
        acc[g] = __builtin_amdgcn_mfma_f32_16x16x32_f16(afh, Wrf[g][kt], acc[g], 0, 0, 0);
    }

    // partials: [wave][n(48)][m(16 pad 20)]; D-frag: n=l15, m=l4h*4+r
#pragma unroll
    for (int g = 0; g < 3; ++g)
      *(f32x4*)&part[wave][g * 16 + l15][l4h * 4] = acc[g];
    __syncthreads();

    float fv = 0.f, ov = 0.f, gv = 0.f;
#pragma unroll
    for (int w = 0; w < 4; ++w) {
      fv += part[w][rd][rb];
      ov += part[w][16 + rd][rb];
      gv += part[w][32 + rd][rb];
    }
    const float sf = sigmoidf_fast(fv);
    const float tg = tanhf_fast(gv);
    c = c * sf + (1.f - sf) * tg;
    const float h = sigmoidf_fast(ov) * tanhf_fast(c);

    out[outidx + (size_t)t * D_] = h;        // plain stores (coherence via barrier)
    hn[hidx] = (_Float16)h;

    bar_arrive(bar, bid, (unsigned)(t + 1));

    // barrier shadow: x-part MFMAs for step t+1 (independent of h)
    if (t + 1 < L_) {
#pragma unroll
      for (int g = 0; g < 3; ++g) { f32x4 z = {0.f, 0.f, 0.f, 0.f}; acc2[g] = z; }
      const _Float16* xr = xrow + (size_t)(t + 1) * D_;
#pragma unroll
      for (int kt = 0; kt < 8; ++kt) {
        half8 afx = *(const half8*)(xr + kt * 32);
#pragma unroll
        for (int g = 0; g < 3; ++g)
          acc2[g] = __builtin_amdgcn_mfma_f32_16x16x32_f16(afx, Wkf[g][kt], acc2[g], 0, 0, 0);
      }
    }

    bar_wait(bar, bid, (unsigned)(t + 1));

#pragma unroll
    for (int g = 0; g < 3; ++g) acc[g] = acc2[g];
    _Float16* tmp = hc; hc = hn; hn = tmp;
  }
}

// ---------------------------------------------------------------------------
extern "C" void kernel_launch(void* const* d_in, const int* in_sizes, int n_in,
                              void* d_out, int out_size, void* d_ws, size_t ws_size,
                              hipStream_t stream) {
  const float* x  = (const float*)d_in[0];
  const float* Wk = (const float*)d_in[1];
  const float* Wr = (const float*)d_in[2];
  const float* c0 = (const float*)d_in[3];
  const float* h0 = (const float*)d_in[4];
  float* out = (float*)d_out;

  char* ws = (char*)d_ws;
  _Float16* WkT = (_Float16*)(ws + WKT_OFF);
  _Float16* WrT = (_Float16*)(ws + WRT_OFF);
  _Float16* xh  = (_Float16*)(ws + XH_OFF);
  _Float16* h16 = (_Float16*)(ws + H16_OFF);
  unsigned* bar = (unsigned*)(ws + BAR_OFF);

  hipMemsetAsync(bar, 0, 4096, stream);

  hipLaunchKernelGGL(transpose_f16, dim3(6144), dim3(256), 0, stream,
                     Wk, Wr, WkT, WrT);
  hipLaunchKernelGGL(convert_inputs, dim3(2048), dim3(256), 0, stream,
                     (const f32x4*)x, (const f32x4*)h0,
                     (half4*)xh, (half4*)h16, (half4*)(h16 + B_ * D_));

  void* kargs[7] = {(void*)&WkT, (void*)&WrT, (void*)&xh, (void*)&c0,
                    (void*)&out, (void*)&h16, (void*)&bar};
  hipLaunchCooperativeKernel((void*)lstm_scan, dim3(256), dim3(256), kargs, 0, stream);
}

// Round 4
// 5160.162 us; speedup vs baseline: 1.2105x; 1.2105x over previous
//
#include <hip/hip_runtime.h>

// ---------------------------------------------------------------------------
// LSTM scan, B=64 L=512 D=1024, fused persistent cooperative kernel.
// Round 4 = round 2 (PASSED) + pinned weights, safer barrier:
//   - Wk,Wr fragments pinned in VGPRs via inline-asm loads (no remat)
//   - h exchange: plain stores/loads + round-2-proven coherence protocol
//     (ACQ_REL counter RMW = release side incl. L2 writeback;
//      relaxed poll + one agent acquire fence = acquire side)
//   - 4 independent barrier groups (one per b-tile, 64 WGs each),
//     MONOTONE counter + flag (no resets -> no ABA hazard)
//   - x@Wk MFMAs for step t+1 in the barrier shadow
// ---------------------------------------------------------------------------

typedef float    f32x4 __attribute__((ext_vector_type(4)));
typedef _Float16 half8 __attribute__((ext_vector_type(8)));
typedef _Float16 half4 __attribute__((ext_vector_type(4)));

#define B_  64
#define L_  512
#define D_  1024
#define N3_ 3072

// ws layout (bytes)
#define WKT_OFF 0LL          // f16 [3072][1024]   6291456
#define WRT_OFF 6291456LL    // f16 [3072][1024]   6291456
#define XH_OFF  12582912LL   // f16 [B*L][1024]   67108864
#define H16_OFF 79691776LL   // f16 [2][64][1024]   262144
#define BAR_OFF 79953920LL   // unsigned[1024]        4096

__device__ __forceinline__ float sigmoidf_fast(float x) {
  return __builtin_amdgcn_rcpf(1.f + __builtin_amdgcn_exp2f(-1.4426950408889634f * x));
}
__device__ __forceinline__ float tanhf_fast(float x) {
  return 1.f - 2.f * __builtin_amdgcn_rcpf(1.f + __builtin_amdgcn_exp2f(2.8853900817779268f * x));
}

// pinned (non-rematerializable) cached 16B load — register allocation only,
// no memory-model games (plain cached load, read-only data).
#define ALOAD(dst, addr) \
  asm volatile("global_load_dwordx4 %0, %1, off" : "=v"(dst) : "v"(addr))
#define VMCNT0() asm volatile("s_waitcnt vmcnt(0)" ::: "memory")

// ---------------- prep: transpose + f32->f16 (Wk and Wr) -------------------
__global__ __launch_bounds__(256) void transpose_f16(
    const float* __restrict__ Wk, const float* __restrict__ Wr,
    _Float16* __restrict__ WkT, _Float16* __restrict__ WrT)
{
  __shared__ float tile[32][33];
  int b = blockIdx.x;
  const float* in = Wk; _Float16* outp = WkT;
  if (b >= 3072) { b -= 3072; in = Wr; outp = WrT; }
  const int n0 = (b % 96) * 32;   // along 3072
  const int k0 = (b / 96) * 32;   // along 1024
  const int tx = threadIdx.x & 31, ty = threadIdx.x >> 5;
#pragma unroll
  for (int i = 0; i < 32; i += 8)
    tile[ty + i][tx] = in[(size_t)(k0 + ty + i) * N3_ + n0 + tx];
  __syncthreads();
#pragma unroll
  for (int i = 0; i < 32; i += 8)
    outp[(size_t)(n0 + ty + i) * D_ + k0 + tx] = (_Float16)tile[tx][ty + i];
}

// ---------------- prep: x -> f16, h0 -> BOTH h16 buffers -------------------
__global__ void convert_inputs(const f32x4* __restrict__ x, const f32x4* __restrict__ h0,
                               half4* __restrict__ xh, half4* __restrict__ h16a,
                               half4* __restrict__ h16b)
{
  const int NX = (B_ * L_ * D_) / 4;
  const int NH = (B_ * D_) / 4;
  for (int i = blockIdx.x * blockDim.x + threadIdx.x; i < NX + NH;
       i += gridDim.x * blockDim.x) {
    if (i < NX) {
      xh[i] = __builtin_convertvector(x[i], half4);
    } else {
      half4 v = __builtin_convertvector(h0[i - NX], half4);
      h16a[i - NX] = v;
      h16b[i - NX] = v;
    }
  }
}

// ---------------- persistent scan ------------------------------------------
// 256 WGs = 4 b-tile groups x 64 d-slices; 4 waves each own a K-slice of 256.
// Per-group monotone barrier: counter at bar[grp*64], flag at bar[grp*64+32].
__global__ __launch_bounds__(256, 1) void lstm_scan(
    const _Float16* __restrict__ WkT,   // [3072][1024]
    const _Float16* __restrict__ WrT,   // [3072][1024]
    const _Float16* __restrict__ xh,    // [B*L][1024]
    const float*    __restrict__ c0,    // [64][1024]
    float*          __restrict__ out,   // [64][512][1024]
    _Float16*       __restrict__ h16,   // [2][64][1024]
    unsigned*       __restrict__ bar)
{
  const int tid = threadIdx.x, wave = tid >> 6, lane = tid & 63;
  const int bid = blockIdx.x;
  const int grp = bid & 3;           // b-tile group (independent scan)
  const int ord = bid >> 2;          // 0..63 within group
  const int b0 = grp * 16;
  const int d0 = ord * 16;
  const int l15 = lane & 15, l4h = lane >> 4;
  const int kbase = wave * 256;

  unsigned* cntp  = bar + grp * 64;        // monotone arrival counter
  unsigned* flagp = bar + grp * 64 + 32;   // monotone step flag

  // ---- stationary weight fragments, pinned via asm loads ----
  half8 Wkf[3][8], Wrf[3][8];
#pragma unroll
  for (int g = 0; g < 3; ++g) {
    const _Float16* kr = WkT + (size_t)(g * D_ + d0 + l15) * D_ + kbase + l4h * 8;
    const _Float16* rr = WrT + (size_t)(g * D_ + d0 + l15) * D_ + kbase + l4h * 8;
#pragma unroll
    for (int kt = 0; kt < 8; ++kt) {
      ALOAD(Wkf[g][kt], kr + kt * 32);
      ALOAD(Wrf[g][kt], rr + kt * 32);
    }
  }
  VMCNT0();

  const int rb = tid >> 4;   // batch within tile
  const int rd = tid & 15;   // d within tile
  float c = c0[(size_t)(b0 + rb) * D_ + d0 + rd];

  __shared__ float part[4][48][20];

  const _Float16* xrow = xh + ((size_t)(b0 + l15) * L_) * D_ + kbase + l4h * 8;
  const size_t hoff   = (size_t)(b0 + l15) * D_ + kbase + l4h * 8;
  const size_t outidx = ((size_t)(b0 + rb) * L_) * D_ + d0 + rd;
  const size_t hidx   = (size_t)(b0 + rb) * D_ + d0 + rd;

  _Float16* hc = h16;            // h_t (both buffers pre-initialized with h0)
  _Float16* hn = h16 + B_ * D_;  // h_{t+1}

  f32x4 acc[3], acc2[3];
#pragma unroll
  for (int g = 0; g < 3; ++g) { f32x4 z = {0.f,0.f,0.f,0.f}; acc[g] = z; acc2[g] = z; }
  // prologue: x-part for t=0
#pragma unroll
  for (int kt = 0; kt < 8; ++kt) {
    half8 afx = *(const half8*)(xrow + kt * 32);
#pragma unroll
    for (int g = 0; g < 3; ++g)
      acc[g] = __builtin_amdgcn_mfma_f32_16x16x32_f16(afx, Wkf[g][kt], acc[g], 0, 0, 0);
  }

  for (int t = 0; t < L_; ++t) {
    // ---- h fragments (plain loads; fresh because of last step's acquire) --
    half8 af[8];
    const _Float16* hrow = hc + hoff;
#pragma unroll
    for (int kt = 0; kt < 8; ++kt) af[kt] = *(const half8*)(hrow + kt * 32);

#pragma unroll
    for (int kt = 0; kt < 8; ++kt)
#pragma unroll
      for (int g = 0; g < 3; ++g)
        acc[g] = __builtin_amdgcn_mfma_f32_16x16x32_f16(af[kt], Wrf[g][kt], acc[g], 0, 0, 0);

    // ---- cross-wave reduce via LDS ----
#pragma unroll
    for (int g = 0; g < 3; ++g)
      *(f32x4*)&part[wave][g * 16 + l15][l4h * 4] = acc[g];
    __syncthreads();

    float fv = 0.f, ov = 0.f, gv = 0.f;
#pragma unroll
    for (int w = 0; w < 4; ++w) {
      fv += part[w][rd][rb];
      ov += part[w][16 + rd][rb];
      gv += part[w][32 + rd][rb];
    }
    const float sf = sigmoidf_fast(fv);
    const float tg = tanhf_fast(gv);
    c = c * sf + (1.f - sf) * tg;
    const float h = sigmoidf_fast(ov) * tanhf_fast(c);

    out[outidx + (size_t)t * D_] = h;    // plain cached stores
    hn[hidx] = (_Float16)h;

    // ---- arrive: ACQ_REL RMW is the release (round-2 proven) ----
    __syncthreads();   // every wave: implicit vmcnt(0) -> all WG stores in L2
    if (tid == 0) {
      unsigned a = __hip_atomic_fetch_add(cntp, 1u, __ATOMIC_ACQ_REL,
                                          __HIP_MEMORY_SCOPE_AGENT);
      if (a == (unsigned)(64 * (t + 1) - 1))   // group closer
        __hip_atomic_store(flagp, (unsigned)(t + 1), __ATOMIC_RELEASE,
                           __HIP_MEMORY_SCOPE_AGENT);
    }

    // ---- barrier shadow: x-part MFMAs for step t+1 ----
    if (t + 1 < L_) {
#pragma unroll
      for (int g = 0; g < 3; ++g) { f32x4 z = {0.f,0.f,0.f,0.f}; acc2[g] = z; }
      const _Float16* xr = xrow + (size_t)(t + 1) * D_;
#pragma unroll
      for (int kt = 0; kt < 8; ++kt) {
        half8 afx = *(const half8*)(xr + kt * 32);
#pragma unroll
        for (int g = 0; g < 3; ++g)
          acc2[g] = __builtin_amdgcn_mfma_f32_16x16x32_f16(afx, Wkf[g][kt], acc2[g], 0, 0, 0);
      }
    }
    __builtin_amdgcn_sched_barrier(0);   // keep shadow work before the wait

    // ---- wait: relaxed poll + ONE agent acquire fence (round-2 proven) ----
    if (tid == 0) {
      while (__hip_atomic_load(flagp, __ATOMIC_RELAXED, __HIP_MEMORY_SCOPE_AGENT)
             < (unsigned)(t + 1)) {
        __builtin_amdgcn_s_sleep(1);
      }
      __builtin_amdgcn_fence(__ATOMIC_ACQUIRE, "agent");  // inv L1+L2 once
    }
    __syncthreads();

#pragma unroll
    for (int g = 0; g < 3; ++g) acc[g] = acc2[g];
    _Float16* tmp = hc; hc = hn; hn = tmp;
  }
}

// ---------------------------------------------------------------------------
extern "C" void kernel_launch(void* const* d_in, const int* in_sizes, int n_in,
                              void* d_out, int out_size, void* d_ws, size_t ws_size,
                              hipStream_t stream) {
  const float* x  = (const float*)d_in[0];
  const float* Wk = (const float*)d_in[1];
  const float* Wr = (const float*)d_in[2];
  const float* c0 = (const float*)d_in[3];
  const float* h0 = (const float*)d_in[4];
  float* out = (float*)d_out;

  char* ws = (char*)d_ws;
  _Float16* WkT = (_Float16*)(ws + WKT_OFF);
  _Float16* WrT = (_Float16*)(ws + WRT_OFF);
  _Float16* xh  = (_Float16*)(ws + XH_OFF);
  _Float16* h16 = (_Float16*)(ws + H16_OFF);
  unsigned* bar = (unsigned*)(ws + BAR_OFF);

  hipMemsetAsync(bar, 0, 4096, stream);

  hipLaunchKernelGGL(transpose_f16, dim3(6144), dim3(256), 0, stream,
                     Wk, Wr, WkT, WrT);
  hipLaunchKernelGGL(convert_inputs, dim3(2048), dim3(256), 0, stream,
                     (const f32x4*)x, (const f32x4*)h0,
                     (half4*)xh, (half4*)h16, (half4*)(h16 + B_ * D_));

  void* kargs[7] = {(void*)&WkT, (void*)&WrT, (void*)&xh, (void*)&c0,
                    (void*)&out, (void*)&h16, (void*)&bar};
  hipLaunchCooperativeKernel((void*)lstm_scan, dim3(256), dim3(256), kargs, 0, stream);
}